// Round 5
// baseline (434.869 us; speedup 1.0000x reference)
//
#include <hip/hip_runtime.h>

// Problem constants: B=8, H=32, W=32, T=4, BS=3, D=768, SMAX=2, P=2560
// Output [B,H,W,T,BS,D] f32. Every (y,x,t) cell covered by exactly one patch.
//
// v4: long-lived waves + prefetched map.
//   Pass 1 (unchanged): cell -> global-patch-id map (131 KB in d_ws).
//   Pass 2: 1024 blocks x 256 thr (4 waves). Each wave owns 8 consecutive
//   cells; all 8 map entries prefetched into scalar regs first (kills the
//   per-cell dependent-load stall), then 72 independent load->nt-store pairs
//   per wave (deep MLP). XCD-bijective: XCD x sweeps cells [x*4096,(x+1)*4096)
//   -> dense sequential writes per XCD + same-XCD L2 reuse of coarse tokens.
//   Rationale: v2 (seq-read/scat-write) == v3 (scat-read/seq-write) within 4%
//   => ordering is not the limiter; the shared structure (tiny short-lived
//   blocks, dependent map load gating 3 load+store pairs) is the suspect.

constexpr int H_ = 32;
constexpr int W_ = 32;
constexpr int T_ = 4;
constexpr int BS_ = 3;
constexpr int D_ = 768;
constexpr int CD  = BS_ * D_;        // 2304 floats per cell
constexpr int CD4 = CD / 4;          // 576 float4 per cell
constexpr int BN_ = 8;
constexpr int CELLS = BN_ * H_ * W_ * T_;   // 32768
constexpr int NXCD = 8;

constexpr int BLOCKS = 1024;              // 128 blocks per XCD
constexpr int WAVES_PER_BLOCK = 4;        // 256 threads
constexpr int TOTAL_WAVES = BLOCKS * WAVES_PER_BLOCK;   // 4096
constexpr int CPW = CELLS / TOTAL_WAVES;  // 8 cells per wave
constexpr int F4_PER_LANE = CD4 / 64;     // 9

typedef float f4 __attribute__((ext_vector_type(4)));

// ---- Pass 1: cell -> global patch id --------------------------------------
__global__ __launch_bounds__(256) void build_map_kernel(
    const int4* __restrict__ pos,   // [B*P] (y, x, size, t)
    int* __restrict__ map,          // [B*H*W*T]
    int P)
{
    const int bp = blockIdx.x * 256 + threadIdx.x;
    if (bp >= BN_ * P) return;
    const int b = bp / P;
    const int4 q = pos[bp];
    const int y = q.x, x = q.y, size = q.z, t = q.w;
    const int c0 = (((b * H_ + y) * W_ + x) * T_) + t;
    map[c0] = bp;
    if (size == 2) {
        map[c0 + T_] = bp;               // (y, x+1)
        map[c0 + W_ * T_] = bp;          // (y+1, x)
        map[c0 + W_ * T_ + T_] = bp;     // (y+1, x+1)
    }
}

// ---- Pass 2: long-lived waves, 8 cells/wave, prefetched map ---------------
__global__ __launch_bounds__(256) void apt_gather2_kernel(
    const f4* __restrict__ tok,     // [B*P, CD4]
    const int* __restrict__ map,    // [CELLS]
    f4* __restrict__ out)           // [CELLS, CD4]
{
    const int blk  = blockIdx.x;
    const int xcd  = blk & (NXCD - 1);     // round-robin block->XCD
    const int jb   = blk >> 3;             // 0..127 within XCD
    const int wv   = threadIdx.x >> 6;     // 0..3
    const int lane = threadIdx.x & 63;

    const int cell0 = xcd * (CELLS / NXCD) + (jb * WAVES_PER_BLOCK + wv) * CPW;

    // Prefetch all 8 map entries (wave-uniform -> scalar loads, one round).
    int pid[CPW];
    #pragma unroll
    for (int c = 0; c < CPW; ++c) pid[c] = map[cell0 + c];

    #pragma unroll
    for (int c = 0; c < CPW; ++c) {
        const f4* __restrict__ src = tok + (long)pid[c] * CD4 + lane;
        f4* __restrict__ dst = out + (long)(cell0 + c) * CD4 + lane;
        #pragma unroll
        for (int k = 0; k < F4_PER_LANE; ++k) {
            const f4 v = src[k * 64];                 // cached: coarse L2 reuse
            __builtin_nontemporal_store(v, &dst[k * 64]); // streaming write
        }
    }
}

// ---- Fallback (v2 scatter) if workspace is too small ----------------------
constexpr int FBLOCK = 192;
__global__ __launch_bounds__(FBLOCK) void apt_scatter_kernel_nt(
    const f4* __restrict__ tok, const int4* __restrict__ pos,
    f4* __restrict__ out, int P)
{
    const int bp = blockIdx.x;
    const int b  = bp / P;
    const int4 q = pos[bp];
    const int y = q.x, x = q.y, size = q.z, t = q.w;
    const f4* __restrict__ src = tok + (long)bp * CD4;
    const long csy = (long)W_ * T_ * CD4;
    const long csx = (long)T_ * CD4;
    const long base0 = ((((long)b * H_ + y) * W_ + x) * T_ + t) * CD4;
    const int tid = threadIdx.x;
    if (size == 1) {
        f4* __restrict__ dst = out + base0;
        #pragma unroll
        for (int k = 0; k < CD4 / FBLOCK; ++k) {
            const int i = tid + k * FBLOCK;
            const f4 v = __builtin_nontemporal_load(&src[i]);
            __builtin_nontemporal_store(v, &dst[i]);
        }
    } else {
        f4* __restrict__ d00 = out + base0;
        f4* __restrict__ d01 = out + base0 + csx;
        f4* __restrict__ d10 = out + base0 + csy;
        f4* __restrict__ d11 = out + base0 + csy + csx;
        #pragma unroll
        for (int k = 0; k < CD4 / FBLOCK; ++k) {
            const int i = tid + k * FBLOCK;
            const f4 v = __builtin_nontemporal_load(&src[i]);
            __builtin_nontemporal_store(v, &d00[i]);
            __builtin_nontemporal_store(v, &d01[i]);
            __builtin_nontemporal_store(v, &d10[i]);
            __builtin_nontemporal_store(v, &d11[i]);
        }
    }
}

extern "C" void kernel_launch(void* const* d_in, const int* in_sizes, int n_in,
                              void* d_out, int out_size, void* d_ws, size_t ws_size,
                              hipStream_t stream) {
    const f4*   tok = (const f4*)d_in[0];     // [B, P*BS, D] f32
    const int4* pos = (const int4*)d_in[1];   // [B, P, 4] i32

    const int P = in_sizes[1] / (BN_ * 4);    // 2560

    const size_t map_bytes = (size_t)CELLS * sizeof(int);
    if (d_ws != nullptr && ws_size >= map_bytes) {
        int* map = (int*)d_ws;
        const int total = BN_ * P;
        build_map_kernel<<<(total + 255) / 256, 256, 0, stream>>>(pos, map, P);
        apt_gather2_kernel<<<BLOCKS, 256, 0, stream>>>(tok, map, (f4*)d_out);
    } else {
        apt_scatter_kernel_nt<<<BN_ * P, FBLOCK, 0, stream>>>(tok, pos, (f4*)d_out, P);
    }
}